// Round 1
// baseline (286.870 us; speedup 1.0000x reference)
//
#include <hip/hip_runtime.h>
#include <cstdint>

#define NB 8192
#define ND 512
#define BM 128
#define BN 128
#define BK 32

typedef __bf16 bf16x8 __attribute__((ext_vector_type(8)));
typedef float f32x4 __attribute__((ext_vector_type(4)));

// round-to-nearest-even f32 -> bf16 bits
__device__ __forceinline__ unsigned short f2bf(float f) {
    union { float f; uint32_t u; } c; c.f = f;
    return (unsigned short)((c.u + 0x7fffu + ((c.u >> 16) & 1u)) >> 16);
}

// async global->LDS, 16B per lane. LDS dest must be wave-uniform; HW adds lane*16.
__device__ __forceinline__ void load16(const void* g, void* l) {
    __builtin_amdgcn_global_load_lds(
        (void __attribute__((address_space(1)))*)(const_cast<void*>(g)),
        (void __attribute__((address_space(3)))*)(l),
        16, 0, 0);
}

// ---------------- kernel 1: L2-normalize rows + cast to bf16 ----------------
// one wave per row; 16384 rows total (8192 video then 8192 text)
__global__ __launch_bounds__(256) void norm_cast(const float* __restrict__ v,
                                                 const float* __restrict__ t,
                                                 unsigned short* __restrict__ vn,
                                                 unsigned short* __restrict__ tn,
                                                 int ns) {
    const int wave = threadIdx.x >> 6;
    const int lane = threadIdx.x & 63;
    const int row = blockIdx.x * 4 + wave;
    const float* src;
    unsigned short* dst;
    if (row < NB) {
        src = v + (size_t)row * ND;
        dst = vn + (size_t)row * ns;
    } else {
        src = t + (size_t)(row - NB) * ND;
        dst = tn + (size_t)(row - NB) * ns;
    }
    // lane handles 8 consecutive floats: [lane*8, lane*8+8)
    float4 a = ((const float4*)src)[lane * 2];
    float4 b = ((const float4*)src)[lane * 2 + 1];
    float ss = a.x * a.x + a.y * a.y + a.z * a.z + a.w * a.w
             + b.x * b.x + b.y * b.y + b.z * b.z + b.w * b.w;
#pragma unroll
    for (int off = 32; off; off >>= 1) ss += __shfl_xor(ss, off);
    const float sc = 1.0f / fmaxf(sqrtf(ss), 1e-12f);
    union { unsigned short us[8]; uint4 q; } pk;
    pk.us[0] = f2bf(a.x * sc); pk.us[1] = f2bf(a.y * sc);
    pk.us[2] = f2bf(a.z * sc); pk.us[3] = f2bf(a.w * sc);
    pk.us[4] = f2bf(b.x * sc); pk.us[5] = f2bf(b.y * sc);
    pk.us[6] = f2bf(b.z * sc); pk.us[7] = f2bf(b.w * sc);
    ((uint4*)dst)[lane] = pk.q;
}

// ---------------- kernel 2: fused bf16 GEMM (V . T^T) + BCE + reduce ----------------
// 128x128 tile, BK=32, 4 waves (2x2), each wave 64x64 via 4x4 16x16x32 MFMA frags.
__global__ __launch_bounds__(256) void gemm_bce(const unsigned short* __restrict__ vn,
                                                const unsigned short* __restrict__ tn,
                                                const float* __restrict__ lt,
                                                const float* __restrict__ bp,
                                                float* __restrict__ out_sum,
                                                int ns) {
    __shared__ __align__(16) unsigned short As[BM * BK];  // [row][k] linear
    __shared__ __align__(16) unsigned short Bs[BN * BK];  // [col][k] linear (T rows)
    __shared__ float red[4];

    const int tid = threadIdx.x;
    const int lane = tid & 63;
    const int wave = tid >> 6;
    const int wr = wave >> 1;
    const int wc = wave & 1;

    const int m0 = (int)(blockIdx.x >> 6) * BM;
    const int n0 = (int)(blockIdx.x & 63) * BN;

    // staging: thread tid loads 16B of row (tid>>2), k-chunk (tid&3)*8
    const int srow = tid >> 2;
    const int sch = (tid & 3) * 8;
    const unsigned short* ap0 = vn + (size_t)(m0 + srow) * ns + sch;
    const unsigned short* ap1 = vn + (size_t)(m0 + 64 + srow) * ns + sch;
    const unsigned short* bq0 = tn + (size_t)(n0 + srow) * ns + sch;
    const unsigned short* bq1 = tn + (size_t)(n0 + 64 + srow) * ns + sch;
    // LDS bases (wave-uniform): linear layout == lane order, 1KB per wave per round
    unsigned short* lA0 = As + wave * 512;
    unsigned short* lA1 = As + 2048 + wave * 512;
    unsigned short* lB0 = Bs + wave * 512;
    unsigned short* lB1 = Bs + 2048 + wave * 512;

    f32x4 acc[4][4];
#pragma unroll
    for (int i = 0; i < 4; ++i)
#pragma unroll
        for (int j = 0; j < 4; ++j)
            acc[i][j] = f32x4{0.f, 0.f, 0.f, 0.f};

    const int arow = wr * 64 + (lane & 15);
    const int brow = wc * 64 + (lane & 15);
    const int kc = (lane >> 4) * 8;

    for (int k0 = 0; k0 < ND; k0 += BK) {
        load16(ap0 + k0, lA0);
        load16(ap1 + k0, lA1);
        load16(bq0 + k0, lB0);
        load16(bq1 + k0, lB1);
        __syncthreads();  // compiler drains vmcnt(0) before barrier -> LDS ready

        bf16x8 af[4], bf[4];
#pragma unroll
        for (int m = 0; m < 4; ++m)
            af[m] = *(const bf16x8*)(As + (arow + m * 16) * BK + kc);
#pragma unroll
        for (int n = 0; n < 4; ++n)
            bf[n] = *(const bf16x8*)(Bs + (brow + n * 16) * BK + kc);
#pragma unroll
        for (int m = 0; m < 4; ++m)
#pragma unroll
            for (int n = 0; n < 4; ++n)
                acc[m][n] = __builtin_amdgcn_mfma_f32_16x16x32_bf16(af[m], bf[n], acc[m][n], 0, 0, 0);
        __syncthreads();  // protect LDS before next stage overwrites
    }

    // epilogue: z = clip(sim*invtemp + bias), bce = max(z,0) - z*label + log1p(exp(-|z|))
    const float invtemp = __expf(-lt[0]);
    const float bias = bp[0];
    float local = 0.f;
    const int row_base = m0 + wr * 64 + ((lane >> 4) << 2);
    const int col_base = n0 + wc * 64 + (lane & 15);
#pragma unroll
    for (int m = 0; m < 4; ++m) {
#pragma unroll
        for (int n = 0; n < 4; ++n) {
#pragma unroll
            for (int r = 0; r < 4; ++r) {
                const float s = acc[m][n][r];
                float z = fminf(fmaxf(s * invtemp + bias, -30.f), 30.f);
                const int gr = row_base + m * 16 + r;
                const int gc = col_base + n * 16;
                const float zl = (gr == gc) ? z : 0.f;
                local += fmaxf(z, 0.f) - zl + log1pf(__expf(-fabsf(z)));
            }
        }
    }
#pragma unroll
    for (int off = 32; off; off >>= 1) local += __shfl_xor(local, off);
    if (lane == 0) red[wave] = local;
    __syncthreads();
    if (tid == 0) atomicAdd(out_sum, red[0] + red[1] + red[2] + red[3]);
}

// ---------------- kernel 3: mean ----------------
__global__ void finalize_k(float* out) {
    out[0] = out[0] * (1.0f / 67108864.0f);  // exact 2^-26
}

extern "C" void kernel_launch(void* const* d_in, const int* in_sizes, int n_in,
                              void* d_out, int out_size, void* d_ws, size_t ws_size,
                              hipStream_t stream) {
    const float* v = (const float*)d_in[0];
    const float* t = (const float*)d_in[1];
    const float* lt = (const float*)d_in[2];
    const float* bp = (const float*)d_in[3];
    float* out = (float*)d_out;

    const size_t need = (size_t)2 * NB * ND * sizeof(unsigned short);
    unsigned short *vn, *tn;
    int ns;
    if (ws_size >= need) {
        vn = (unsigned short*)d_ws;
        tn = vn + (size_t)NB * ND;
        ns = ND;
    } else {
        // emergency fallback: pack bf16 into the (harness-restored) input buffers
        vn = (unsigned short*)d_in[0];
        tn = (unsigned short*)d_in[1];
        ns = ND * 2;
    }

    hipMemsetAsync(out, 0, sizeof(float), stream);
    hipLaunchKernelGGL(norm_cast, dim3((2 * NB) / 4), dim3(256), 0, stream, v, t, vn, tn, ns);
    hipLaunchKernelGGL(gemm_bce, dim3((NB / BM) * (NB / BN)), dim3(256), 0, stream,
                       vn, tn, lt, bp, out, ns);
    hipLaunchKernelGGL(finalize_k, dim3(1), dim3(1), 0, stream, out);
}

// Round 2
// 196.006 us; speedup vs baseline: 1.4636x; 1.4636x over previous
//
#include <hip/hip_runtime.h>
#include <cstdint>

#define NB 8192
#define ND 512
#define BM 128
#define BN 128
#define BK 64
#define NT (ND / BK)

typedef __bf16 bf16x8 __attribute__((ext_vector_type(8)));
typedef float f32x4 __attribute__((ext_vector_type(4)));

// round-to-nearest-even f32 -> bf16 bits
__device__ __forceinline__ unsigned short f2bf(float f) {
    union { float f; uint32_t u; } c; c.f = f;
    return (unsigned short)((c.u + 0x7fffu + ((c.u >> 16) & 1u)) >> 16);
}

// async global->LDS, 16B per lane. LDS dest is wave-uniform; HW adds lane*16.
__device__ __forceinline__ void load16(const void* g, void* l) {
    __builtin_amdgcn_global_load_lds(
        (void __attribute__((address_space(1)))*)(const_cast<void*>(g)),
        (void __attribute__((address_space(3)))*)(l),
        16, 0, 0);
}

// ---------------- kernel 1: L2-normalize rows + cast to bf16 ----------------
__global__ __launch_bounds__(256) void norm_cast(const float* __restrict__ v,
                                                 const float* __restrict__ t,
                                                 unsigned short* __restrict__ vn,
                                                 unsigned short* __restrict__ tn,
                                                 int ns) {
    const int wave = threadIdx.x >> 6;
    const int lane = threadIdx.x & 63;
    const int row = blockIdx.x * 4 + wave;
    const float* src;
    unsigned short* dst;
    if (row < NB) {
        src = v + (size_t)row * ND;
        dst = vn + (size_t)row * ns;
    } else {
        src = t + (size_t)(row - NB) * ND;
        dst = tn + (size_t)(row - NB) * ns;
    }
    float4 a = ((const float4*)src)[lane * 2];
    float4 b = ((const float4*)src)[lane * 2 + 1];
    float ss = a.x * a.x + a.y * a.y + a.z * a.z + a.w * a.w
             + b.x * b.x + b.y * b.y + b.z * b.z + b.w * b.w;
#pragma unroll
    for (int off = 32; off; off >>= 1) ss += __shfl_xor(ss, off);
    const float sc = 1.0f / fmaxf(sqrtf(ss), 1e-12f);
    union { unsigned short us[8]; uint4 q; } pk;
    pk.us[0] = f2bf(a.x * sc); pk.us[1] = f2bf(a.y * sc);
    pk.us[2] = f2bf(a.z * sc); pk.us[3] = f2bf(a.w * sc);
    pk.us[4] = f2bf(b.x * sc); pk.us[5] = f2bf(b.y * sc);
    pk.us[6] = f2bf(b.z * sc); pk.us[7] = f2bf(b.w * sc);
    ((uint4*)dst)[lane] = pk.q;
}

// ---------------- kernel 2: fused bf16 GEMM (V . T^T) + BCE + reduce ----------------
// 128x128 tile, BK=64, 4 waves (2x2), each wave 64x64 via 4x4 16x16x32 MFMA frags.
// LDS layout XOR-swizzled: row r, 16B-chunk c stored at chunk slot (c ^ (r&7)).
// global_load_lds writes linearly, so the SOURCE chunk is pre-swizzled per lane.
__global__ __launch_bounds__(256) void gemm_bce(const unsigned short* __restrict__ vn,
                                                const unsigned short* __restrict__ tn,
                                                const float* __restrict__ lt,
                                                const float* __restrict__ bp,
                                                float* __restrict__ out_sum,
                                                int ns) {
    __shared__ __align__(16) unsigned short As[BM * BK];  // 16 KB
    __shared__ __align__(16) unsigned short Bs[BN * BK];  // 16 KB
    __shared__ float red[4];

    const int tid = threadIdx.x;
    const int lane = tid & 63;
    const int wave = tid >> 6;
    const int wr = wave >> 1;
    const int wc = wave & 1;

    const int m0 = (int)(blockIdx.x >> 6) * BM;
    const int n0 = (int)(blockIdx.x & 63) * BN;

    // ---- staging addresses (pre-swizzled source chunks) ----
    // each load16 issue covers 8 rows x 64 k (1 KB). lane l -> row (l>>3),
    // source chunk (l&7)^((l>>3)&7), so linear LDS write == swizzled layout.
    const int srow = lane >> 3;                     // 0..7
    const int schunk = (lane & 7) ^ (srow & 7);     // pre-swizzled 16B chunk
    const unsigned short* ap[4];
    const unsigned short* bq[4];
#pragma unroll
    for (int i = 0; i < 4; ++i) {
        const int rA = m0 + wave * 32 + i * 8 + srow;
        const int rB = n0 + wave * 32 + i * 8 + srow;
        ap[i] = vn + (size_t)rA * ns + schunk * 8;
        bq[i] = tn + (size_t)rB * ns + schunk * 8;
    }

    f32x4 acc[4][4];
#pragma unroll
    for (int i = 0; i < 4; ++i)
#pragma unroll
        for (int j = 0; j < 4; ++j)
            acc[i][j] = f32x4{0.f, 0.f, 0.f, 0.f};

    const int lq = lane & 15;
    const int lh = lane >> 4;
    const int swz0 = lh ^ (lane & 7);   // chunk slot for ks=0; ks=1 is swz0^4

    for (int t = 0; t < NT; ++t) {
        const int k0 = t * BK;
#pragma unroll
        for (int i = 0; i < 4; ++i) {
            load16(ap[i] + k0, As + (wave * 32 + i * 8) * BK);
            load16(bq[i] + k0, Bs + (wave * 32 + i * 8) * BK);
        }
        __syncthreads();  // compiler drains vmcnt(0) before barrier -> LDS ready

#pragma unroll
        for (int ks = 0; ks < 2; ++ks) {
            const int csw = (swz0 ^ (ks * 4)) * 8;
            bf16x8 af[4], bf[4];
#pragma unroll
            for (int m = 0; m < 4; ++m)
                af[m] = *(const bf16x8*)(As + (wr * 64 + m * 16 + lq) * BK + csw);
#pragma unroll
            for (int n = 0; n < 4; ++n)
                bf[n] = *(const bf16x8*)(Bs + (wc * 64 + n * 16 + lq) * BK + csw);
#pragma unroll
            for (int m = 0; m < 4; ++m)
#pragma unroll
                for (int n = 0; n < 4; ++n)
                    acc[m][n] = __builtin_amdgcn_mfma_f32_16x16x32_bf16(af[m], bf[n], acc[m][n], 0, 0, 0);
        }
        __syncthreads();  // protect LDS before next stage overwrites
    }

    // epilogue: z = clip(sim/temp + bias); bce = max(z,0) - z*[diag] + log1p(exp(-|z|))
    // fast softplus tail via hw v_exp/v_log: log(1 + exp(-|z|)); error << 2.5e-5 budget
    const float invtemp = __expf(-lt[0]);
    const float bias = bp[0];
    float local = 0.f;
    const int row_base = m0 + wr * 64 + lh * 4;
    const int col_base = n0 + wc * 64 + lq;
#pragma unroll
    for (int m = 0; m < 4; ++m) {
#pragma unroll
        for (int n = 0; n < 4; ++n) {
#pragma unroll
            for (int r = 0; r < 4; ++r) {
                const float s = acc[m][n][r];
                float z = fminf(fmaxf(fmaf(s, invtemp, bias), -30.f), 30.f);
                const int gr = row_base + m * 16 + r;
                const int gc = col_base + n * 16;
                float term = fmaxf(z, 0.f) + __logf(1.0f + __expf(-fabsf(z)));
                local += term - ((gr == gc) ? z : 0.f);
            }
        }
    }
#pragma unroll
    for (int off = 32; off; off >>= 1) local += __shfl_xor(local, off);
    if (lane == 0) red[wave] = local;
    __syncthreads();
    if (tid == 0) atomicAdd(out_sum, red[0] + red[1] + red[2] + red[3]);
}

// ---------------- kernel 3: mean ----------------
__global__ void finalize_k(float* out) {
    out[0] = out[0] * (1.0f / 67108864.0f);  // exact 2^-26
}

extern "C" void kernel_launch(void* const* d_in, const int* in_sizes, int n_in,
                              void* d_out, int out_size, void* d_ws, size_t ws_size,
                              hipStream_t stream) {
    const float* v = (const float*)d_in[0];
    const float* t = (const float*)d_in[1];
    const float* lt = (const float*)d_in[2];
    const float* bp = (const float*)d_in[3];
    float* out = (float*)d_out;

    const size_t need = (size_t)2 * NB * ND * sizeof(unsigned short);
    unsigned short *vn, *tn;
    int ns;
    if (ws_size >= need) {
        vn = (unsigned short*)d_ws;
        tn = vn + (size_t)NB * ND;
        ns = ND;
    } else {
        vn = (unsigned short*)d_in[0];
        tn = (unsigned short*)d_in[1];
        ns = ND * 2;
    }

    hipMemsetAsync(out, 0, sizeof(float), stream);
    hipLaunchKernelGGL(norm_cast, dim3((2 * NB) / 4), dim3(256), 0, stream, v, t, vn, tn, ns);
    hipLaunchKernelGGL(gemm_bce, dim3((NB / BM) * (NB / BN)), dim3(256), 0, stream,
                       vn, tn, lt, bp, out, ns);
    hipLaunchKernelGGL(finalize_k, dim3(1), dim3(1), 0, stream, out);
}

// Round 4
// 179.656 us; speedup vs baseline: 1.5968x; 1.0910x over previous
//
#include <hip/hip_runtime.h>
#include <cstdint>

#define NB 8192
#define ND 512
#define BM 256
#define BN 256
#define BK 32
#define NT (ND / BK)   // 16 K-tiles
#define THREADS 512

typedef __bf16 bf16x8 __attribute__((ext_vector_type(8)));
typedef float f32x4 __attribute__((ext_vector_type(4)));

// round-to-nearest-even f32 -> bf16 bits
__device__ __forceinline__ unsigned short f2bf(float f) {
    union { float f; uint32_t u; } c; c.f = f;
    return (unsigned short)((c.u + 0x7fffu + ((c.u >> 16) & 1u)) >> 16);
}

// async global->LDS, 16B per lane. LDS dest is wave-uniform; HW adds lane*16.
__device__ __forceinline__ void load16(const void* g, void* l) {
    __builtin_amdgcn_global_load_lds(
        (void __attribute__((address_space(1)))*)(const_cast<void*>(g)),
        (void __attribute__((address_space(3)))*)(l),
        16, 0, 0);
}

// ---------------- kernel 1: L2-normalize rows + cast to bf16 ----------------
__global__ __launch_bounds__(256) void norm_cast(const float* __restrict__ v,
                                                 const float* __restrict__ t,
                                                 unsigned short* __restrict__ vn,
                                                 unsigned short* __restrict__ tn,
                                                 int ns) {
    const int wave = threadIdx.x >> 6;
    const int lane = threadIdx.x & 63;
    const int row = blockIdx.x * 4 + wave;
    const float* src;
    unsigned short* dst;
    if (row < NB) {
        src = v + (size_t)row * ND;
        dst = vn + (size_t)row * ns;
    } else {
        src = t + (size_t)(row - NB) * ND;
        dst = tn + (size_t)(row - NB) * ns;
    }
    float4 a = ((const float4*)src)[lane * 2];
    float4 b = ((const float4*)src)[lane * 2 + 1];
    float ss = a.x * a.x + a.y * a.y + a.z * a.z + a.w * a.w
             + b.x * b.x + b.y * b.y + b.z * b.z + b.w * b.w;
#pragma unroll
    for (int off = 32; off; off >>= 1) ss += __shfl_xor(ss, off);
    const float sc = 1.0f / fmaxf(sqrtf(ss), 1e-12f);
    union { unsigned short us[8]; uint4 q; } pk;
    pk.us[0] = f2bf(a.x * sc); pk.us[1] = f2bf(a.y * sc);
    pk.us[2] = f2bf(a.z * sc); pk.us[3] = f2bf(a.w * sc);
    pk.us[4] = f2bf(b.x * sc); pk.us[5] = f2bf(b.y * sc);
    pk.us[6] = f2bf(b.z * sc); pk.us[7] = f2bf(b.w * sc);
    ((uint4*)dst)[lane] = pk.q;
}

// ---------------- kernel 2: pipelined bf16 GEMM (V . T^T) + BCE + reduce ----------------
// 256x256 tile, BK=32, 8 waves (2Mx4N), 3-buffer LDS rotation, counted vmcnt.
// Liveness: group t computes buf[t%3]; stages tile t+2 into buf[(t+2)%3], which
// was last read in group t-1 (before that group's ending barrier). End-of-group
// wait vmcnt(4) leaves tile t+2's 4 issues in flight, guarantees tile t+1 (the
// wave's older 4 issues) resident; barrier makes that true for ALL waves.
// LDS swizzle: row r, natural 16B chunk c stored at slot c^(r&3); staging
// pre-swizzles the per-lane GLOBAL source chunk so linear global_load_lds
// writes produce the swizzled layout (both-sides-or-neither rule).
__global__ __launch_bounds__(THREADS) void gemm_bce(const unsigned short* __restrict__ vn,
                                                    const unsigned short* __restrict__ tn,
                                                    const float* __restrict__ lt,
                                                    const float* __restrict__ bp,
                                                    float* __restrict__ out_sum,
                                                    int ns) {
    __shared__ __align__(16) unsigned short smem[3 * 2 * BM * BK];  // 96 KB
    __shared__ float red[8];

    const int tid = threadIdx.x;
    const int lane = tid & 63;
    const int wave = tid >> 6;     // 0..7
    const int wr = wave >> 2;      // 0..1  (M half)
    const int wc = wave & 3;       // 0..3  (N quarter)
    const int lq = lane & 15;
    const int lh = lane >> 4;      // 0..3 (k-slice)

    const int m0 = (int)(blockIdx.x >> 5) * BM;
    const int n0 = (int)(blockIdx.x & 31) * BN;

    // staging: one issue = 512 threads x 16B = 128 rows x 64B. thread tid ->
    // row tid>>2, dest slot tid&3; source chunk pre-swizzled = (tid&3)^(row&3).
    const int srow = tid >> 2;
    const int schunk = (tid & 3) ^ (srow & 3);
    const unsigned short* a0 = vn + (size_t)(m0 + srow) * ns + schunk * 8;
    const unsigned short* a1 = vn + (size_t)(m0 + 128 + srow) * ns + schunk * 8;
    const unsigned short* b0 = tn + (size_t)(n0 + srow) * ns + schunk * 8;
    const unsigned short* b1 = tn + (size_t)(n0 + 128 + srow) * ns + schunk * 8;

#define STAGE(t, b) do {                                                   \
        const int k0_ = (t) * BK;                                          \
        unsigned short* As_ = smem + (b) * (2 * BM * BK);                  \
        unsigned short* Bs_ = As_ + BM * BK;                               \
        load16(a0 + k0_, As_ + wave * 512);                                \
        load16(a1 + k0_, As_ + 4096 + wave * 512);                         \
        load16(b0 + k0_, Bs_ + wave * 512);                                \
        load16(b1 + k0_, Bs_ + 4096 + wave * 512);                         \
    } while (0)

    // reader offsets (shorts): row R, natural chunk lh -> slot lh^(R&3)
    const int swz = (lh ^ (lq & 3)) * 8;
    const int aoff = (wr * 128 + lq) * BK + swz;
    const int boff = (wc * 64 + lq) * BK + swz;

    f32x4 acc[8][4];
#pragma unroll
    for (int m = 0; m < 8; ++m)
#pragma unroll
        for (int n = 0; n < 4; ++n)
            acc[m][n] = f32x4{0.f, 0.f, 0.f, 0.f};

    // prologue: stage tiles 0,1; wait own-oldest-4 (tile0) landed; barrier.
    STAGE(0, 0);
    STAGE(1, 1);
    asm volatile("s_waitcnt vmcnt(4)" ::: "memory");
    __builtin_amdgcn_s_barrier();
    __builtin_amdgcn_sched_barrier(0);

#pragma unroll
    for (int t = 0; t < NT; ++t) {
        const unsigned short* As_ = smem + (t % 3) * (2 * BM * BK);
        const unsigned short* Bs_ = As_ + BM * BK;
        bf16x8 af[8], bfr[4];
#pragma unroll
        for (int m = 0; m < 8; ++m)
            af[m] = *(const bf16x8*)(As_ + aoff + m * 512);
#pragma unroll
        for (int n = 0; n < 4; ++n)
            bfr[n] = *(const bf16x8*)(Bs_ + boff + n * 512);

        if (t + 2 < NT) STAGE(t + 2, (t + 2) % 3);

        __builtin_amdgcn_s_setprio(1);
#pragma unroll
        for (int m = 0; m < 8; ++m)
#pragma unroll
            for (int n = 0; n < 4; ++n)
                acc[m][n] = __builtin_amdgcn_mfma_f32_16x16x32_bf16(af[m], bfr[n], acc[m][n], 0, 0, 0);
        __builtin_amdgcn_s_setprio(0);

        if (t < NT - 2) {
            asm volatile("s_waitcnt vmcnt(4)" ::: "memory");
            __builtin_amdgcn_s_barrier();
            __builtin_amdgcn_sched_barrier(0);
        } else if (t == NT - 2) {
            asm volatile("s_waitcnt vmcnt(0)" ::: "memory");
            __builtin_amdgcn_s_barrier();
            __builtin_amdgcn_sched_barrier(0);
        }
    }
#undef STAGE

    // epilogue: z = clip(sim/temp + bias); bce = max(z,0) - z*[diag] + log(1+exp(-|z|))
    const float invtemp = __expf(-lt[0]);
    const float bias = bp[0];
    float local = 0.f;
    const int row_base = m0 + wr * 128 + lh * 4;
    const int col_base = n0 + wc * 64 + lq;
#pragma unroll
    for (int m = 0; m < 8; ++m) {
#pragma unroll
        for (int n = 0; n < 4; ++n) {
#pragma unroll
            for (int r = 0; r < 4; ++r) {
                const float s = acc[m][n][r];
                float z = fminf(fmaxf(fmaf(s, invtemp, bias), -30.f), 30.f);
                const int gr = row_base + m * 16 + r;
                const int gc = col_base + n * 16;
                local += fmaxf(z, 0.f) + __logf(1.0f + __expf(-fabsf(z))) - ((gr == gc) ? z : 0.f);
            }
        }
    }
#pragma unroll
    for (int off = 32; off; off >>= 1) local += __shfl_xor(local, off);
    if (lane == 0) red[wave] = local;
    __syncthreads();
    if (tid == 0) {
        float tot = 0.f;
#pragma unroll
        for (int w = 0; w < 8; ++w) tot += red[w];
        atomicAdd(out_sum, tot * (1.0f / 67108864.0f));  // fold exact 2^-26 mean scale
    }
}

extern "C" void kernel_launch(void* const* d_in, const int* in_sizes, int n_in,
                              void* d_out, int out_size, void* d_ws, size_t ws_size,
                              hipStream_t stream) {
    const float* v = (const float*)d_in[0];
    const float* t = (const float*)d_in[1];
    const float* lt = (const float*)d_in[2];
    const float* bp = (const float*)d_in[3];
    float* out = (float*)d_out;

    const size_t need = (size_t)2 * NB * ND * sizeof(unsigned short);
    unsigned short *vn, *tn;
    int ns;
    if (ws_size >= need) {
        vn = (unsigned short*)d_ws;
        tn = vn + (size_t)NB * ND;
        ns = ND;
    } else {
        vn = (unsigned short*)d_in[0];
        tn = (unsigned short*)d_in[1];
        ns = ND * 2;
    }

    hipMemsetAsync(out, 0, sizeof(float), stream);
    hipLaunchKernelGGL(norm_cast, dim3((2 * NB) / 4), dim3(256), 0, stream, v, t, vn, tn, ns);
    hipLaunchKernelGGL(gemm_bce, dim3((NB / BM) * (NB / BN)), dim3(THREADS), 0, stream,
                       vn, tn, lt, bp, out, ns);
}

// Round 5
// 177.472 us; speedup vs baseline: 1.6164x; 1.0123x over previous
//
#include <hip/hip_runtime.h>
#include <cstdint>

#define NB 8192
#define ND 512
#define BM 256
#define BN 256
#define BK 64
#define NT (ND / BK)   // 8 K-tiles
#define THREADS 512

typedef __bf16 bf16x8 __attribute__((ext_vector_type(8)));
typedef float f32x4 __attribute__((ext_vector_type(4)));

__device__ __forceinline__ unsigned short f2bf(float f) {
    union { float f; uint32_t u; } c; c.f = f;
    return (unsigned short)((c.u + 0x7fffu + ((c.u >> 16) & 1u)) >> 16);
}

// async global->LDS, 16B per lane. LDS dest must be wave-uniform; HW adds lane*16.
__device__ __forceinline__ void load16(const void* g, void* l) {
    __builtin_amdgcn_global_load_lds(
        (void __attribute__((address_space(1)))*)(const_cast<void*>(g)),
        (void __attribute__((address_space(3)))*)(l),
        16, 0, 0);
}

// ---------------- kernel 1: L2-normalize rows + cast to bf16 ----------------
__global__ __launch_bounds__(256) void norm_cast(const float* __restrict__ v,
                                                 const float* __restrict__ t,
                                                 unsigned short* __restrict__ vn,
                                                 unsigned short* __restrict__ tn,
                                                 int ns) {
    const int wave = threadIdx.x >> 6;
    const int lane = threadIdx.x & 63;
    const int row = blockIdx.x * 4 + wave;
    const float* src;
    unsigned short* dst;
    if (row < NB) { src = v + (size_t)row * ND; dst = vn + (size_t)row * ns; }
    else { src = t + (size_t)(row - NB) * ND; dst = tn + (size_t)(row - NB) * ns; }
    float4 a = ((const float4*)src)[lane * 2];
    float4 b = ((const float4*)src)[lane * 2 + 1];
    float ss = a.x * a.x + a.y * a.y + a.z * a.z + a.w * a.w
             + b.x * b.x + b.y * b.y + b.z * b.z + b.w * b.w;
#pragma unroll
    for (int off = 32; off; off >>= 1) ss += __shfl_xor(ss, off);
    const float sc = 1.0f / fmaxf(sqrtf(ss), 1e-12f);
    union { unsigned short us[8]; uint4 q; } pk;
    pk.us[0] = f2bf(a.x * sc); pk.us[1] = f2bf(a.y * sc);
    pk.us[2] = f2bf(a.z * sc); pk.us[3] = f2bf(a.w * sc);
    pk.us[4] = f2bf(b.x * sc); pk.us[5] = f2bf(b.y * sc);
    pk.us[6] = f2bf(b.z * sc); pk.us[7] = f2bf(b.w * sc);
    ((uint4*)dst)[lane] = pk.q;
}

// ---------------- kernel 2: 8-phase pipelined bf16 GEMM + BCE + reduce ----------------
// 256x256 tile, BK=64, 8 waves. 2 LDS buffers (128 KB). 4 phases per K-tile,
// 16 MFMA each. Fragment remap localizes consumption: A rows = m*32+wr*16
// (m<4 <-> A-half0), B cols = n*64+wc*16 (n<2 <-> B-half0). Per phase: ds-reads
// + 1 half-tile stage (2 x global_load_lds) + barrier + lgkmcnt(0) + 16 MFMA +
// counted vmcnt + barrier. Steady-state vmcnt(6) = 3 half-tiles in flight.
// Swizzle (both-sides): row r, natural 16B chunk c stored at slot c^(r&7);
// stage pre-swizzles the per-lane GLOBAL source chunk (linear LDS dest).
__global__ __launch_bounds__(THREADS, 2) void gemm_bce(const unsigned short* __restrict__ vn,
                                                       const unsigned short* __restrict__ tn,
                                                       const float* __restrict__ lt,
                                                       const float* __restrict__ bp,
                                                       float* __restrict__ out_sum,
                                                       int ns) {
    __shared__ __align__(16) unsigned short smem[2 * 2 * BM * BK];  // 128 KB: [buf][A|B][256][64]
    __shared__ float red[8];

    const int tid = threadIdx.x;
    const int lane = tid & 63;
    const int wave = tid >> 6;     // 0..7
    const int wr = wave >> 2;      // 0..1
    const int wc = wave & 3;       // 0..3
    const int lq = lane & 15;
    const int lh = lane >> 4;      // 0..3

    const int m0 = (int)(blockIdx.x >> 5) * BM;
    const int n0 = (int)(blockIdx.x & 31) * BN;

    // ---- staging source (pre-swizzled): thread tid -> row tid>>3, dest slot
    // tid&7, so natural source chunk = (tid&7) ^ ((tid>>3)&7).
    const int sr = tid >> 3;                       // 0..63
    const int sc = (tid & 7) ^ (sr & 7);           // source 16B chunk
    const unsigned short* sA = vn + (size_t)(m0 + sr) * ns + sc * 8;
    const unsigned short* sB = tn + (size_t)(n0 + sr) * ns + sc * 8;

    // one STG = one half-tile (128 rows x 64 K) = 2 x load16 (8 KB each).
    // wave w writes rows {base + w*8 .. +7} of each 64-row issue block.
#define STG_A(B, T, H) do {                                                    \
        unsigned short* _d = smem + (B) * 32768 + (((H) * 128) + wave * 8) * 64; \
        load16(sA + (size_t)((H) * 128) * ns + (T) * 64, _d);                  \
        load16(sA + (size_t)((H) * 128 + 64) * ns + (T) * 64, _d + 4096);      \
    } while (0)
#define STG_B(B, T, H) do {                                                    \
        unsigned short* _d = smem + (B) * 32768 + 16384 + (((H) * 128) + wave * 8) * 64; \
        load16(sB + (size_t)((H) * 128) * ns + (T) * 64, _d);                  \
        load16(sB + (size_t)((H) * 128 + 64) * ns + (T) * 64, _d + 4096);      \
    } while (0)

    // ---- reader offsets (shorts). Local A row for frag m: m*32 + wr*16 + lq.
    // natural chunk for (ks,lh) = ks*4+lh; read slot = chunk ^ (row&7), row&7 = lq&7.
    const int s0 = ((lh ^ (lq & 7)) * 8);          // ks=0 slot offset; ks=1 = s0^32
    const int aro = (wr * 16 + lq) * 64;
    const int bro = (wc * 16 + lq) * 64;
#define RD_A(C, M, KS) (*(const bf16x8*)(smem + (C) * 32768 + aro + (M) * 2048 + ((KS) ? (s0 ^ 32) : s0)))
#define RD_B(C, N, KS) (*(const bf16x8*)(smem + (C) * 32768 + 16384 + bro + (N) * 4096 + ((KS) ? (s0 ^ 32) : s0)))

#define BAR __builtin_amdgcn_s_barrier()
#define SCB __builtin_amdgcn_sched_barrier(0)
#define LGK0 asm volatile("s_waitcnt lgkmcnt(0)" ::: "memory")
#define VM12 asm volatile("s_waitcnt vmcnt(12)" ::: "memory")
#define VM10 asm volatile("s_waitcnt vmcnt(10)" ::: "memory")
#define VM8  asm volatile("s_waitcnt vmcnt(8)" ::: "memory")
#define VM6  asm volatile("s_waitcnt vmcnt(6)" ::: "memory")
#define VM4  asm volatile("s_waitcnt vmcnt(4)" ::: "memory")
#define VM2  asm volatile("s_waitcnt vmcnt(2)" ::: "memory")
#define VM0  asm volatile("s_waitcnt vmcnt(0)" ::: "memory")
#define VMNONE ((void)0)

    f32x4 acc[8][4];
#pragma unroll
    for (int m = 0; m < 8; ++m)
#pragma unroll
        for (int n = 0; n < 4; ++n)
            acc[m][n] = f32x4{0.f, 0.f, 0.f, 0.f};

    bf16x8 afr[4][2], bfr[4][2];

#define MFMA16(MB, N0)                                                          \
    _Pragma("unroll") for (int mm = 0; mm < 4; ++mm)                            \
    _Pragma("unroll") for (int nn = 0; nn < 2; ++nn)                            \
    _Pragma("unroll") for (int kk = 0; kk < 2; ++kk)                            \
        acc[(MB) + mm][(N0) + nn] = __builtin_amdgcn_mfma_f32_16x16x32_bf16(    \
            afr[mm][kk], bfr[(N0) + nn][kk], acc[(MB) + mm][(N0) + nn], 0, 0, 0)

    // 4 phases per tile. S123: stage (T+1)'s Bh0/Bh1/Ah1 at P1/P2/P3.
    // S4: stage (T+2)'s Ah0 at P4 (goes into buf (T)&1 — dead since P1(T)).
#define TILE_BODY(T, S123, S4, W1, W2, W4) do {                                 \
        const int _cb = (T) & 1, _nb = _cb ^ 1;                                 \
        /* P1: A-half0 + B-half0 reads */                                       \
        _Pragma("unroll") for (int mm = 0; mm < 4; ++mm) {                      \
            afr[mm][0] = RD_A(_cb, mm, 0); afr[mm][1] = RD_A(_cb, mm, 1); }     \
        _Pragma("unroll") for (int nn = 0; nn < 2; ++nn) {                      \
            bfr[nn][0] = RD_B(_cb, nn, 0); bfr[nn][1] = RD_B(_cb, nn, 1); }     \
        if (S123) STG_B(_nb, (T) + 1, 0);                                       \
        BAR; LGK0; SCB;                                                         \
        __builtin_amdgcn_s_setprio(1); MFMA16(0, 0);                            \
        __builtin_amdgcn_s_setprio(0); W1; BAR; SCB;                            \
        /* P2: B-half1 reads */                                                 \
        _Pragma("unroll") for (int nn = 2; nn < 4; ++nn) {                      \
            bfr[nn][0] = RD_B(_cb, nn, 0); bfr[nn][1] = RD_B(_cb, nn, 1); }     \
        if (S123) STG_B(_nb, (T) + 1, 1);                                       \
        BAR; LGK0; SCB;                                                         \
        __builtin_amdgcn_s_setprio(1); MFMA16(0, 2);                            \
        __builtin_amdgcn_s_setprio(0); W2; BAR; SCB;                            \
        /* P3: A-half1 reads (bf0 held in regs) */                              \
        _Pragma("unroll") for (int mm = 0; mm < 4; ++mm) {                      \
            afr[mm][0] = RD_A(_cb, mm + 4, 0); afr[mm][1] = RD_A(_cb, mm + 4, 1); } \
        if (S123) STG_A(_nb, (T) + 1, 1);                                       \
        BAR; LGK0; SCB;                                                         \
        __builtin_amdgcn_s_setprio(1); MFMA16(4, 0);                            \
        __builtin_amdgcn_s_setprio(0); BAR; SCB;                                \
        /* P4: no reads (af,bf1 held) */                                        \
        if (S4) STG_A(_cb, (T) + 2, 0);                                         \
        BAR; SCB;                                                               \
        __builtin_amdgcn_s_setprio(1); MFMA16(4, 2);                            \
        __builtin_amdgcn_s_setprio(0); W4; BAR; SCB;                            \
    } while (0)

    // prologue: tiles 0,1 fully staged in consumption order (Ah0,Bh0,Bh1,Ah1)
    STG_A(0, 0, 0); STG_B(0, 0, 0); STG_B(0, 0, 1); STG_A(0, 0, 1);
    STG_A(1, 1, 0); STG_B(1, 1, 0); STG_B(1, 1, 1); STG_A(1, 1, 1);
    VM12; BAR; SCB;

    TILE_BODY(0, false, true, VM10, VM8, VM6);   // t1 pre-staged; P4 stages t2-Ah0
    for (int t = 1; t <= 6; ++t) {
        const bool s4 = (t <= 5);
        TILE_BODY(t, true, s4, VM6, VM6, VM6);
    }
    TILE_BODY(7, false, false, VM2, VM0, VMNONE);

    // epilogue: z = clip(sim/temp + bias); bce = max(z,0) - z*[diag] + log(1+exp(-|z|))
    const float invtemp = __expf(-lt[0]);
    const float bias = bp[0];
    float local = 0.f;
    const int row_base = m0 + wr * 16 + lh * 4;
    const int col_base = n0 + wc * 16 + lq;
#pragma unroll
    for (int m = 0; m < 8; ++m) {
#pragma unroll
        for (int n = 0; n < 4; ++n) {
#pragma unroll
            for (int r = 0; r < 4; ++r) {
                const float s = acc[m][n][r];
                float z = fminf(fmaxf(fmaf(s, invtemp, bias), -30.f), 30.f);
                const int gr = row_base + m * 32 + r;
                const int gc = col_base + n * 64;
                local += fmaxf(z, 0.f) + __logf(1.0f + __expf(-fabsf(z))) - ((gr == gc) ? z : 0.f);
            }
        }
    }
#pragma unroll
    for (int off = 32; off; off >>= 1) local += __shfl_xor(local, off);
    if (lane == 0) red[wave] = local;
    __syncthreads();
    if (tid == 0) {
        float tot = 0.f;
#pragma unroll
        for (int w = 0; w < 8; ++w) tot += red[w];
        atomicAdd(out_sum, tot * (1.0f / 67108864.0f));  // exact 2^-26 mean scale
    }
}

extern "C" void kernel_launch(void* const* d_in, const int* in_sizes, int n_in,
                              void* d_out, int out_size, void* d_ws, size_t ws_size,
                              hipStream_t stream) {
    const float* v = (const float*)d_in[0];
    const float* t = (const float*)d_in[1];
    const float* lt = (const float*)d_in[2];
    const float* bp = (const float*)d_in[3];
    float* out = (float*)d_out;

    const size_t need = (size_t)2 * NB * ND * sizeof(unsigned short);
    unsigned short *vn, *tn;
    int ns;
    if (ws_size >= need) {
        vn = (unsigned short*)d_ws;
        tn = vn + (size_t)NB * ND;
        ns = ND;
    } else {
        vn = (unsigned short*)d_in[0];
        tn = (unsigned short*)d_in[1];
        ns = ND * 2;
    }

    hipMemsetAsync(out, 0, sizeof(float), stream);
    hipLaunchKernelGGL(norm_cast, dim3((2 * NB) / 4), dim3(256), 0, stream, v, t, vn, tn, ns);
    hipLaunchKernelGGL(gemm_bce, dim3((NB / BM) * (NB / BN)), dim3(THREADS), 0, stream,
                       vn, tn, lt, bp, out, ns);
}

// Round 7
// 176.460 us; speedup vs baseline: 1.6257x; 1.0057x over previous
//
#include <hip/hip_runtime.h>
#include <cstdint>

#define NB 8192
#define ND 512
#define BM 256
#define BN 256
#define BK 64
#define NT (ND / BK)   // 8 K-tiles
#define THREADS 512

typedef __bf16 bf16x8 __attribute__((ext_vector_type(8)));
typedef float f32x4 __attribute__((ext_vector_type(4)));

__device__ __forceinline__ unsigned short f2bf(float f) {
    union { float f; uint32_t u; } c; c.f = f;
    return (unsigned short)((c.u + 0x7fffu + ((c.u >> 16) & 1u)) >> 16);
}

// async global->LDS, 16B per lane. LDS dest must be wave-uniform; HW adds lane*16.
__device__ __forceinline__ void load16(const void* g, void* l) {
    __builtin_amdgcn_global_load_lds(
        (void __attribute__((address_space(1)))*)(const_cast<void*>(g)),
        (void __attribute__((address_space(3)))*)(l),
        16, 0, 0);
}

// ---------------- kernel 1: L2-normalize rows + cast to bf16 ----------------
__global__ __launch_bounds__(256) void norm_cast(const float* __restrict__ v,
                                                 const float* __restrict__ t,
                                                 unsigned short* __restrict__ vn,
                                                 unsigned short* __restrict__ tn,
                                                 int ns) {
    const int wave = threadIdx.x >> 6;
    const int lane = threadIdx.x & 63;
    const int row = blockIdx.x * 4 + wave;
    const float* src;
    unsigned short* dst;
    if (row < NB) { src = v + (size_t)row * ND; dst = vn + (size_t)row * ns; }
    else { src = t + (size_t)(row - NB) * ND; dst = tn + (size_t)(row - NB) * ns; }
    float4 a = ((const float4*)src)[lane * 2];
    float4 b = ((const float4*)src)[lane * 2 + 1];
    float ss = a.x * a.x + a.y * a.y + a.z * a.z + a.w * a.w
             + b.x * b.x + b.y * b.y + b.z * b.z + b.w * b.w;
#pragma unroll
    for (int off = 32; off; off >>= 1) ss += __shfl_xor(ss, off);
    const float sc = 1.0f / fmaxf(sqrtf(ss), 1e-12f);
    union { unsigned short us[8]; uint4 q; } pk;
    pk.us[0] = f2bf(a.x * sc); pk.us[1] = f2bf(a.y * sc);
    pk.us[2] = f2bf(a.z * sc); pk.us[3] = f2bf(a.w * sc);
    pk.us[4] = f2bf(b.x * sc); pk.us[5] = f2bf(b.y * sc);
    pk.us[6] = f2bf(b.z * sc); pk.us[7] = f2bf(b.w * sc);
    ((uint4*)dst)[lane] = pk.q;
}

// ---------------- kernel 2: 8-phase pipelined bf16 GEMM + BCE + reduce ----------------
// Same schedule as R5 (verified: conflicts 0, absmax 0) but the K-tile loop is
// FULLY UNROLLED: compile-time T folds buffer selects / LDS addresses into
// immediates, removing the ~100 VALU ops/phase of runtime address recompute
// that showed as VALUBusy=47% on the critical path.
__global__ __launch_bounds__(THREADS, 2) void gemm_bce(const unsigned short* __restrict__ vn,
                                                       const unsigned short* __restrict__ tn,
                                                       const float* __restrict__ lt,
                                                       const float* __restrict__ bp,
                                                       float* __restrict__ out_sum,
                                                       int ns) {
    __shared__ __align__(16) unsigned short smem[2 * 2 * BM * BK];  // 128 KB: [buf][A|B][256][64]
    __shared__ float red[8];

    const int tid = threadIdx.x;
    const int lane = tid & 63;
    const int wave = tid >> 6;     // 0..7
    const int wr = wave >> 2;      // 0..1
    const int wc = wave & 3;       // 0..3
    const int lq = lane & 15;
    const int lh = lane >> 4;      // 0..3

    const int m0 = (int)(blockIdx.x >> 5) * BM;
    const int n0 = (int)(blockIdx.x & 31) * BN;

    // staging source (pre-swizzled): thread tid -> row tid>>3, dest slot tid&7,
    // natural source chunk = (tid&7) ^ ((tid>>3)&7).
    const int sr = tid >> 3;                       // 0..63
    const int sc = (tid & 7) ^ (sr & 7);           // source 16B chunk
    const unsigned short* sA = vn + (size_t)(m0 + sr) * ns + sc * 8;
    const unsigned short* sB = tn + (size_t)(n0 + sr) * ns + sc * 8;

#define STG_A(B, T, H) do {                                                    \
        unsigned short* _d = smem + (B) * 32768 + (((H) * 128) + wave * 8) * 64; \
        load16(sA + (size_t)((H) * 128) * ns + (T) * 64, _d);                  \
        load16(sA + (size_t)((H) * 128 + 64) * ns + (T) * 64, _d + 4096);      \
    } while (0)
#define STG_B(B, T, H) do {                                                    \
        unsigned short* _d = smem + (B) * 32768 + 16384 + (((H) * 128) + wave * 8) * 64; \
        load16(sB + (size_t)((H) * 128) * ns + (T) * 64, _d);                  \
        load16(sB + (size_t)((H) * 128 + 64) * ns + (T) * 64, _d + 4096);      \
    } while (0)

    // reader offsets (shorts). A row for frag m: m*32 + wr*16 + lq.
    // natural chunk (ks,lh) = ks*4+lh; slot = chunk ^ (row&7), row&7 = lq&7.
    const int s0 = ((lh ^ (lq & 7)) * 8);
    const int aro = (wr * 16 + lq) * 64;
    const int bro = (wc * 16 + lq) * 64;
#define RD_A(C, M, KS) (*(const bf16x8*)(smem + (C) * 32768 + aro + (M) * 2048 + ((KS) ? (s0 ^ 32) : s0)))
#define RD_B(C, N, KS) (*(const bf16x8*)(smem + (C) * 32768 + 16384 + bro + (N) * 4096 + ((KS) ? (s0 ^ 32) : s0)))

#define BAR __builtin_amdgcn_s_barrier()
#define SCB __builtin_amdgcn_sched_barrier(0)
#define LGK0 asm volatile("s_waitcnt lgkmcnt(0)" ::: "memory")
#define VM12 asm volatile("s_waitcnt vmcnt(12)" ::: "memory")
#define VM10 asm volatile("s_waitcnt vmcnt(10)" ::: "memory")
#define VM8  asm volatile("s_waitcnt vmcnt(8)" ::: "memory")
#define VM6  asm volatile("s_waitcnt vmcnt(6)" ::: "memory")
#define VM2  asm volatile("s_waitcnt vmcnt(2)" ::: "memory")
#define VM0  asm volatile("s_waitcnt vmcnt(0)" ::: "memory")
#define VMNONE ((void)0)

    f32x4 acc[8][4];
#pragma unroll
    for (int m = 0; m < 8; ++m)
#pragma unroll
        for (int n = 0; n < 4; ++n)
            acc[m][n] = f32x4{0.f, 0.f, 0.f, 0.f};

    bf16x8 afr[4][2], bfr[4][2];

#define MFMA16(MB, N0)                                                          \
    _Pragma("unroll") for (int mm = 0; mm < 4; ++mm)                            \
    _Pragma("unroll") for (int nn = 0; nn < 2; ++nn)                            \
    _Pragma("unroll") for (int kk = 0; kk < 2; ++kk)                            \
        acc[(MB) + mm][(N0) + nn] = __builtin_amdgcn_mfma_f32_16x16x32_bf16(    \
            afr[mm][kk], bfr[(N0) + nn][kk], acc[(MB) + mm][(N0) + nn], 0, 0, 0)

    // 4 phases per tile. S123: stage (T+1)'s Bh0/Bh1/Ah1 at P1/P2/P3.
    // S4: stage (T+2)'s Ah0 at P4 (into buf (T)&1 -- that region dead since P1(T)).
    // Steady-state invariant: 6 loads outstanding entering each P1.
#define TILE_BODY(T, S123, S4, W1, W2, W4) do {                                 \
        /* P1: A-half0 + B-half0 reads */                                       \
        _Pragma("unroll") for (int mm = 0; mm < 4; ++mm) {                      \
            afr[mm][0] = RD_A((T) & 1, mm, 0); afr[mm][1] = RD_A((T) & 1, mm, 1); } \
        _Pragma("unroll") for (int nn = 0; nn < 2; ++nn) {                      \
            bfr[nn][0] = RD_B((T) & 1, nn, 0); bfr[nn][1] = RD_B((T) & 1, nn, 1); } \
        if (S123) STG_B(((T) & 1) ^ 1, (T) + 1, 0);                             \
        BAR; LGK0; SCB;                                                         \
        __builtin_amdgcn_s_setprio(1); MFMA16(0, 0);                            \
        __builtin_amdgcn_s_setprio(0); W1; BAR; SCB;                            \
        /* P2: B-half1 reads */                                                 \
        _Pragma("unroll") for (int nn = 2; nn < 4; ++nn) {                      \
            bfr[nn][0] = RD_B((T) & 1, nn, 0); bfr[nn][1] = RD_B((T) & 1, nn, 1); } \
        if (S123) STG_B(((T) & 1) ^ 1, (T) + 1, 1);                             \
        BAR; LGK0; SCB;                                                         \
        __builtin_amdgcn_s_setprio(1); MFMA16(0, 2);                            \
        __builtin_amdgcn_s_setprio(0); W2; BAR; SCB;                            \
        /* P3: A-half1 reads (bf0 held in regs) */                              \
        _Pragma("unroll") for (int mm = 0; mm < 4; ++mm) {                      \
            afr[mm][0] = RD_A((T) & 1, mm + 4, 0); afr[mm][1] = RD_A((T) & 1, mm + 4, 1); } \
        if (S123) STG_A(((T) & 1) ^ 1, (T) + 1, 1);                             \
        BAR; LGK0; SCB;                                                         \
        __builtin_amdgcn_s_setprio(1); MFMA16(4, 0);                            \
        __builtin_amdgcn_s_setprio(0); BAR; SCB;                                \
        /* P4: no reads (af,bf1 held) */                                        \
        if (S4) STG_A((T) & 1, (T) + 2, 0);                                     \
        BAR; SCB;                                                               \
        __builtin_amdgcn_s_setprio(1); MFMA16(4, 2);                            \
        __builtin_amdgcn_s_setprio(0); W4; BAR; SCB;                            \
    } while (0)

    // prologue: tiles 0,1 fully staged in consumption order (Ah0,Bh0,Bh1,Ah1)
    STG_A(0, 0, 0); STG_B(0, 0, 0); STG_B(0, 0, 1); STG_A(0, 0, 1);
    STG_A(1, 1, 0); STG_B(1, 1, 0); STG_B(1, 1, 1); STG_A(1, 1, 1);
    VM12; BAR; SCB;

    // fully unrolled K-loop: compile-time T everywhere
    TILE_BODY(0, false, true,  VM10, VM8, VM6);
    TILE_BODY(1, true,  true,  VM6,  VM6, VM6);
    TILE_BODY(2, true,  true,  VM6,  VM6, VM6);
    TILE_BODY(3, true,  true,  VM6,  VM6, VM6);
    TILE_BODY(4, true,  true,  VM6,  VM6, VM6);
    TILE_BODY(5, true,  true,  VM6,  VM6, VM6);
    TILE_BODY(6, true,  false, VM6,  VM6, VM6);
    TILE_BODY(7, false, false, VM2,  VM0, VMNONE);

    // epilogue: z = clip(sim/temp + bias); bce = max(z,0) - z*[diag] + log(1+exp(-|z|))
    const float invtemp = __expf(-lt[0]);
    const float bias = bp[0];
    float local = 0.f;
    const int row_base = m0 + wr * 16 + lh * 4;
    const int col_base = n0 + wc * 16 + lq;
#pragma unroll
    for (int m = 0; m < 8; ++m) {
#pragma unroll
        for (int n = 0; n < 4; ++n) {
#pragma unroll
            for (int r = 0; r < 4; ++r) {
                const float s = acc[m][n][r];
                float z = fminf(fmaxf(fmaf(s, invtemp, bias), -30.f), 30.f);
                const int gr = row_base + m * 32 + r;
                const int gc = col_base + n * 64;
                local += fmaxf(z, 0.f) + __logf(1.0f + __expf(-fabsf(z))) - ((gr == gc) ? z : 0.f);
            }
        }
    }
#pragma unroll
    for (int off = 32; off; off >>= 1) local += __shfl_xor(local, off);
    if (lane == 0) red[wave] = local;
    __syncthreads();
    if (tid == 0) {
        float tot = 0.f;
#pragma unroll
        for (int w = 0; w < 8; ++w) tot += red[w];
        atomicAdd(out_sum, tot * (1.0f / 67108864.0f));  // exact 2^-26 mean scale
    }
}

extern "C" void kernel_launch(void* const* d_in, const int* in_sizes, int n_in,
                              void* d_out, int out_size, void* d_ws, size_t ws_size,
                              hipStream_t stream) {
    const float* v = (const float*)d_in[0];
    const float* t = (const float*)d_in[1];
    const float* lt = (const float*)d_in[2];
    const float* bp = (const float*)d_in[3];
    float* out = (float*)d_out;

    const size_t need = (size_t)2 * NB * ND * sizeof(unsigned short);
    unsigned short *vn, *tn;
    int ns;
    if (ws_size >= need) {
        vn = (unsigned short*)d_ws;
        tn = vn + (size_t)NB * ND;
        ns = ND;
    } else {
        vn = (unsigned short*)d_in[0];
        tn = (unsigned short*)d_in[1];
        ns = ND * 2;
    }

    hipMemsetAsync(out, 0, sizeof(float), stream);
    hipLaunchKernelGGL(norm_cast, dim3((2 * NB) / 4), dim3(256), 0, stream, v, t, vn, tn, ns);
    hipLaunchKernelGGL(gemm_bce, dim3((NB / BM) * (NB / BN)), dim3(THREADS), 0, stream,
                       vn, tn, lt, bp, out, ns);
}

// Round 9
// 176.276 us; speedup vs baseline: 1.6274x; 1.0010x over previous
//
#include <hip/hip_runtime.h>
#include <cstdint>

#define NB 8192
#define ND 512
#define BM 256
#define BN 256
#define BK 32
#define NTL (ND / BK)   // 16 K-tiles
#define THREADS 512
#define BUFS 16384      // shorts per buffer (32 KB: A 16KB + B 16KB)

typedef __bf16 bf16x8 __attribute__((ext_vector_type(8)));
typedef float f32x4 __attribute__((ext_vector_type(4)));

__device__ __forceinline__ unsigned short f2bf(float f) {
    union { float f; uint32_t u; } c; c.f = f;
    return (unsigned short)((c.u + 0x7fffu + ((c.u >> 16) & 1u)) >> 16);
}

// async global->LDS, 16B per lane. LDS dest must be wave-uniform; HW adds lane*16.
__device__ __forceinline__ void load16(const void* g, void* l) {
    __builtin_amdgcn_global_load_lds(
        (void __attribute__((address_space(1)))*)(const_cast<void*>(g)),
        (void __attribute__((address_space(3)))*)(l),
        16, 0, 0);
}

// ---------------- kernel 1: L2-normalize rows + cast to bf16 ----------------
__global__ __launch_bounds__(256) void norm_cast(const float* __restrict__ v,
                                                 const float* __restrict__ t,
                                                 unsigned short* __restrict__ vn,
                                                 unsigned short* __restrict__ tn,
                                                 int ns) {
    const int wave = threadIdx.x >> 6;
    const int lane = threadIdx.x & 63;
    const int row = blockIdx.x * 4 + wave;
    const float* src;
    unsigned short* dst;
    if (row < NB) { src = v + (size_t)row * ND; dst = vn + (size_t)row * ns; }
    else { src = t + (size_t)(row - NB) * ND; dst = tn + (size_t)(row - NB) * ns; }
    float4 a = ((const float4*)src)[lane * 2];
    float4 b = ((const float4*)src)[lane * 2 + 1];
    float ss = a.x * a.x + a.y * a.y + a.z * a.z + a.w * a.w
             + b.x * b.x + b.y * b.y + b.z * b.z + b.w * b.w;
#pragma unroll
    for (int off = 32; off; off >>= 1) ss += __shfl_xor(ss, off);
    const float sc = 1.0f / fmaxf(sqrtf(ss), 1e-12f);
    union { unsigned short us[8]; uint4 q; } pk;
    pk.us[0] = f2bf(a.x * sc); pk.us[1] = f2bf(a.y * sc);
    pk.us[2] = f2bf(a.z * sc); pk.us[3] = f2bf(a.w * sc);
    pk.us[4] = f2bf(b.x * sc); pk.us[5] = f2bf(b.y * sc);
    pk.us[6] = f2bf(b.z * sc); pk.us[7] = f2bf(b.w * sc);
    ((uint4*)dst)[lane] = pk.q;
}

// ---------------- kernel 2: cluster-ahead pipelined bf16 GEMM + BCE ----------------
// 256x256 tile, BK=32, 8 waves (2Mx4N, wave tile 128x64), 3 LDS buffers (96 KB).
// ONE barrier per K-tile. Per tile: c0 reads (8xb128) -> c1 reads (4xb128) ->
// stage tile T+2 -> MFMA c0 (compiler-counted lgkmcnt(4): c1 reads complete
// UNDER c0's MFMAs) -> MFMA c1 -> vmcnt(4) (loads issued a tile ago) -> barrier.
// LDS/MFMA pipes overlap instead of serializing (R7 was 2025 cyc/phase vs 592 MFMA).
// Swizzle (64B rows): row r chunk c at slot c^((r>>1)&3); 16-lane pass -> 8 slots,
// 2-way = free. Staging pre-swizzles the GLOBAL source chunk (linear LDS dest).
__global__ __launch_bounds__(THREADS, 2) void gemm_bce(const unsigned short* __restrict__ vn,
                                                       const unsigned short* __restrict__ tn,
                                                       const float* __restrict__ lt,
                                                       const float* __restrict__ bp,
                                                       float* __restrict__ out_sum,
                                                       int ns) {
    __shared__ __align__(16) unsigned short smem[3 * BUFS];  // 96 KB
    __shared__ float red[8];

    const int tid = threadIdx.x;
    const int lane = tid & 63;
    const int wave = tid >> 6;     // 0..7
    const int wr = wave >> 2;      // 0..1
    const int wc = wave & 3;       // 0..3
    const int lq = lane & 15;
    const int lh = lane >> 4;      // 0..3

    const int m0 = (int)(blockIdx.x >> 5) * BM;
    const int n0 = (int)(blockIdx.x & 31) * BN;

    // staging: per wave, one tile = A rows [32w..32w+31] + B rows [32w..32w+31],
    // 2 load16 each (16 rows x 64B = 1KB per issue). lane l -> row +(l>>2),
    // source chunk (l&3)^((l>>3)&3) (pre-swizzled so linear LDS dest == swizzled).
    const int schunk = ((lane & 3) ^ ((lane >> 3) & 3)) * 8;
    const unsigned short* sA = vn + (size_t)(m0 + 32 * wave + (lane >> 2)) * ns + schunk;
    const unsigned short* sB = tn + (size_t)(n0 + 32 * wave + (lane >> 2)) * ns + schunk;

#define STG(T, B) do {                                                         \
        unsigned short* _dA = smem + (B) * BUFS + wave * 1024;                 \
        unsigned short* _dB = _dA + 8192;                                      \
        load16(sA + (T) * 32, _dA);                                            \
        load16(sA + (T) * 32 + (size_t)16 * ns, _dA + 512);                    \
        load16(sB + (T) * 32, _dB);                                            \
        load16(sB + (T) * 32 + (size_t)16 * ns, _dB + 512);                    \
    } while (0)

    // reader offsets (shorts): row stride 32. frag k-chunk = lh (k = lh*8..+7),
    // slot = lh ^ ((row>>1)&3); row = ...16*w + lq -> ((lq>>1)&3) lane-constant.
    const int sl = (lh ^ ((lq >> 1) & 3)) * 8;
    const int aro = (wr * 16 + lq) * 32 + sl;
    const int bro = (wc * 16 + lq) * 32 + sl;
#define RD_A(C, M) (*(const bf16x8*)(smem + (C) * BUFS + aro + (M) * 1024))
#define RD_B(C, N) (*(const bf16x8*)(smem + (C) * BUFS + 8192 + bro + (N) * 2048))

#define BAR __builtin_amdgcn_s_barrier()
#define SCB __builtin_amdgcn_sched_barrier(0)
#define VM4 asm volatile("s_waitcnt vmcnt(4)" ::: "memory")
#define VM0 asm volatile("s_waitcnt vmcnt(0)" ::: "memory")

    f32x4 acc[8][4];
#pragma unroll
    for (int m = 0; m < 8; ++m)
#pragma unroll
        for (int n = 0; n < 4; ++n)
            acc[m][n] = f32x4{0.f, 0.f, 0.f, 0.f};

    bf16x8 afr[8], bfr[4];

    // TILE(T): S = stage tile T+2, WMODE: 0=VM4+BAR, 1=VM0+BAR, 2=none (last)
#define TILE(T, S, WMODE) do {                                                  \
        /* c0 reads: A[0-3], B[0-3] of buf T%3 */                               \
        _Pragma("unroll") for (int mm = 0; mm < 4; ++mm) afr[mm] = RD_A((T) % 3, mm); \
        _Pragma("unroll") for (int nn = 0; nn < 4; ++nn) bfr[nn] = RD_B((T) % 3, nn); \
        SCB;                                                                    \
        /* c1 reads: A[4-7] -- complete under MFMA c0 via compiler lgkm(4) */   \
        _Pragma("unroll") for (int mm = 4; mm < 8; ++mm) afr[mm] = RD_A((T) % 3, mm); \
        if (S) STG((T) + 2, ((T) + 2) % 3);                                     \
        SCB;                                                                    \
        __builtin_amdgcn_s_setprio(1);                                          \
        _Pragma("unroll") for (int mm = 0; mm < 4; ++mm)                        \
        _Pragma("unroll") for (int nn = 0; nn < 4; ++nn)                        \
            acc[mm][nn] = __builtin_amdgcn_mfma_f32_16x16x32_bf16(              \
                afr[mm], bfr[nn], acc[mm][nn], 0, 0, 0);                        \
        __builtin_amdgcn_s_setprio(0); SCB;                                     \
        __builtin_amdgcn_s_setprio(1);                                          \
        _Pragma("unroll") for (int mm = 4; mm < 8; ++mm)                        \
        _Pragma("unroll") for (int nn = 0; nn < 4; ++nn)                        \
            acc[mm][nn] = __builtin_amdgcn_mfma_f32_16x16x32_bf16(              \
                afr[mm], bfr[nn], acc[mm][nn], 0, 0, 0);                        \
        __builtin_amdgcn_s_setprio(0); SCB;                                     \
        if ((WMODE) == 0) { VM4; BAR; SCB; }                                    \
        else if ((WMODE) == 1) { VM0; BAR; SCB; }                               \
    } while (0)

    // prologue: stage tiles 0,1; wait tile0's 4 (8 outstanding -> 4); barrier.
    STG(0, 0);
    STG(1, 1);
    VM4; BAR; SCB;

    TILE(0,  true, 0);  TILE(1,  true, 0);  TILE(2,  true, 0);  TILE(3,  true, 0);
    TILE(4,  true, 0);  TILE(5,  true, 0);  TILE(6,  true, 0);  TILE(7,  true, 0);
    TILE(8,  true, 0);  TILE(9,  true, 0);  TILE(10, true, 0);  TILE(11, true, 0);
    TILE(12, true, 0);  TILE(13, true, 0);  TILE(14, false, 1); TILE(15, false, 2);

    // epilogue: z = clip(sim/temp + bias); bce = max(z,0) - z*[diag] + log(1+exp(-|z|))
    const float invtemp = __expf(-lt[0]);
    const float bias = bp[0];
    float local = 0.f;
    const int row_base = m0 + wr * 16 + lh * 4;
    const int col_base = n0 + wc * 16 + lq;
#pragma unroll
    for (int m = 0; m < 8; ++m) {
#pragma unroll
        for (int n = 0; n < 4; ++n) {
#pragma unroll
            for (int r = 0; r < 4; ++r) {
                const float s = acc[m][n][r];
                float z = fminf(fmaxf(fmaf(s, invtemp, bias), -30.f), 30.f);
                const int gr = row_base + m * 32 + r;
                const int gc = col_base + n * 64;
                local += fmaxf(z, 0.f) + __logf(1.0f + __expf(-fabsf(z))) - ((gr == gc) ? z : 0.f);
            }
        }
    }
#pragma unroll
    for (int off = 32; off; off >>= 1) local += __shfl_xor(local, off);
    if (lane == 0) red[wave] = local;
    __syncthreads();
    if (tid == 0) {
        float tot = 0.f;
#pragma unroll
        for (int w = 0; w < 8; ++w) tot += red[w];
        atomicAdd(out_sum, tot * (1.0f / 67108864.0f));  // exact 2^-26 mean scale
    }
}

extern "C" void kernel_launch(void* const* d_in, const int* in_sizes, int n_in,
                              void* d_out, int out_size, void* d_ws, size_t ws_size,
                              hipStream_t stream) {
    const float* v = (const float*)d_in[0];
    const float* t = (const float*)d_in[1];
    const float* lt = (const float*)d_in[2];
    const float* bp = (const float*)d_in[3];
    float* out = (float*)d_out;

    const size_t need = (size_t)2 * NB * ND * sizeof(unsigned short);
    unsigned short *vn, *tn;
    int ns;
    if (ws_size >= need) {
        vn = (unsigned short*)d_ws;
        tn = vn + (size_t)NB * ND;
        ns = ND;
    } else {
        vn = (unsigned short*)d_in[0];
        tn = (unsigned short*)d_in[1];
        ns = ND * 2;
    }

    hipMemsetAsync(out, 0, sizeof(float), stream);
    hipLaunchKernelGGL(norm_cast, dim3((2 * NB) / 4), dim3(256), 0, stream, v, t, vn, tn, ns);
    hipLaunchKernelGGL(gemm_bce, dim3((NB / BM) * (NB / BN)), dim3(THREADS), 0, stream,
                       vn, tn, lt, bp, out, ns);
}